// Round 1
// baseline (170.214 us; speedup 1.0000x reference)
//
#include <hip/hip_runtime.h>
#include <hip/hip_bf16.h>

#define K_DIM 4096
#define M_DIM 4096
#define T_DIM 2048
#define NB    1024
#define BT    64     // t rows per workgroup tile

typedef __attribute__((ext_vector_type(8))) short bf16x8;
typedef __attribute__((ext_vector_type(4))) float f32x4;

__device__ __forceinline__ unsigned short f2bf(float f) {
    unsigned int u = __builtin_bit_cast(unsigned int, f);
    unsigned int r = (u + 0x7FFFu + ((u >> 16) & 1u)) >> 16;
    return (unsigned short)r;
}

__global__ __launch_bounds__(256, 2) void fsl_mfma_kernel(
    const float* __restrict__ x, const float* __restrict__ values,
    const float* __restrict__ bias, const int* __restrict__ brows,
    const int* __restrict__ bcols, float* __restrict__ out)
{
    // LDS: double-buffered A (x tile) and B (values tile), 64x64 bf16 each,
    // XOR-swizzled (byte ^= (row&7)<<4) to kill ds_read_b128 bank conflicts.
    __shared__ __align__(16) unsigned char sA[2][64 * 128];
    __shared__ __align__(16) unsigned char sB[2][64 * 128];
    __shared__ int s_list[NB];
    __shared__ int s_cnt;

    const int tid = threadIdx.x;
    const int r   = blockIdx.x >> 5;          // row-group 0..63
    const int t0  = (blockIdx.x & 31) * BT;   // t tile base

    if (tid == 0) s_cnt = 0;
    __syncthreads();
    for (int n = tid; n < NB; n += 256) {
        if (brows[n] == r) {
            int p = atomicAdd(&s_cnt, 1);
            s_list[p] = n;
        }
    }
    __syncthreads();
    const int cnt = s_cnt;

    // wave decomposition: 2x2 waves over (t, m), each wave owns 32t x 32m
    const int wave = tid >> 6;
    const int lane = tid & 63;
    const int wt   = wave >> 1;
    const int wm   = wave & 1;
    const int lrow = lane & 15;
    const int lk8  = (lane >> 4) * 8;

    // staging decomposition: 16x16 threads, each thread 4 rows x 1 float4
    const int srow = tid >> 4;   // 0..15
    const int scol = tid & 15;   // 0..15

    f32x4 acc[2][2] = {};
    float4 ra[4], rb[4];

    auto stage_load = [&](int i) {
        const int n = s_list[i];
        const int c = bcols[n];
        const float* xp = x + (size_t)(t0 + srow) * K_DIM + c * 64 + scol * 4;
        const float* vp = values + (size_t)n * 4096 + srow * 64 + scol * 4;
#pragma unroll
        for (int j = 0; j < 4; ++j) {
            ra[j] = *(const float4*)(xp + (size_t)(j * 16) * K_DIM);
            rb[j] = *(const float4*)(vp + j * 16 * 64);
        }
    };

    auto stage_write = [&](int buf) {
#pragma unroll
        for (int j = 0; j < 4; ++j) {
            const int row = srow + j * 16;
            int byte = row * 128 + scol * 8;
            byte ^= (row & 7) << 4;
            uint2 pa, pb;
            pa.x = (unsigned int)f2bf(ra[j].x) | ((unsigned int)f2bf(ra[j].y) << 16);
            pa.y = (unsigned int)f2bf(ra[j].z) | ((unsigned int)f2bf(ra[j].w) << 16);
            pb.x = (unsigned int)f2bf(rb[j].x) | ((unsigned int)f2bf(rb[j].y) << 16);
            pb.y = (unsigned int)f2bf(rb[j].z) | ((unsigned int)f2bf(rb[j].w) << 16);
            *(uint2*)(&sA[buf][byte]) = pa;
            *(uint2*)(&sB[buf][byte]) = pb;
        }
    };

    auto compute = [&](int buf) {
#pragma unroll
        for (int ks = 0; ks < 2; ++ks) {
            bf16x8 a[2], b[2];
#pragma unroll
            for (int f = 0; f < 2; ++f) {
                const int trow = wt * 32 + f * 16 + lrow;
                int abyte = trow * 128 + (ks * 32 + lk8) * 2;
                abyte ^= (trow & 7) << 4;
                a[f] = *(const bf16x8*)(&sA[buf][abyte]);
                const int mrow = wm * 32 + f * 16 + lrow;
                int bbyte = mrow * 128 + (ks * 32 + lk8) * 2;
                bbyte ^= (mrow & 7) << 4;
                b[f] = *(const bf16x8*)(&sB[buf][bbyte]);
            }
#pragma unroll
            for (int ft = 0; ft < 2; ++ft)
#pragma unroll
                for (int fm = 0; fm < 2; ++fm)
                    acc[ft][fm] = __builtin_amdgcn_mfma_f32_16x16x32_bf16(
                        a[ft], b[fm], acc[ft][fm], 0, 0, 0);
        }
    };

    if (cnt > 0) { stage_load(0); stage_write(0); }
    for (int i = 0; i < cnt; ++i) {
        __syncthreads();                 // buf[i&1] staged & prev reads done
        const bool more = (i + 1 < cnt);
        if (more) stage_load(i + 1);     // issue global loads early (T14)
        compute(i & 1);                  // MFMA hides load latency
        if (more) stage_write((i + 1) & 1);
    }

    // Epilogue: C/D layout col = lane&15, row = (lane>>4)*4 + reg
    const int mcol  = lane & 15;
    const int trow4 = (lane >> 4) * 4;
#pragma unroll
    for (int ft = 0; ft < 2; ++ft) {
#pragma unroll
        for (int fm = 0; fm < 2; ++fm) {
            const int mg = r * 64 + wm * 32 + fm * 16 + mcol;
            const float bv = bias[mg];
#pragma unroll
            for (int reg = 0; reg < 4; ++reg) {
                const int t = t0 + wt * 32 + ft * 16 + trow4 + reg;
                float v = acc[ft][fm][reg] + bv;
                float inner = 0.7978845608f * (v + 0.044715f * v * v * v);
                inner = fminf(fmaxf(inner, -15.0f), 15.0f);
                const float e  = __expf(2.0f * inner);
                const float th = 1.0f - 2.0f / (e + 1.0f);
                out[(size_t)t * M_DIM + mg] = v * 0.5f * (1.0f + th);
            }
        }
    }
}

extern "C" void kernel_launch(void* const* d_in, const int* in_sizes, int n_in,
                              void* d_out, int out_size, void* d_ws, size_t ws_size,
                              hipStream_t stream) {
    const float* x      = (const float*)d_in[0];
    const float* values = (const float*)d_in[1];
    const float* bias   = (const float*)d_in[2];
    const int*   brows  = (const int*)d_in[3];
    const int*   bcols  = (const int*)d_in[4];
    float* out = (float*)d_out;

    dim3 grid(64 * 32);   // 64 row-groups x 32 t-tiles
    fsl_mfma_kernel<<<grid, 256, 0, stream>>>(x, values, bias, brows, bcols, out);
}

// Round 3
// 142.777 us; speedup vs baseline: 1.1922x; 1.1922x over previous
//
#include <hip/hip_runtime.h>
#include <hip/hip_bf16.h>

#define K_DIM 4096
#define M_DIM 4096
#define T_DIM 2048
#define NB    1024

typedef __attribute__((ext_vector_type(8))) short bf16x8;
typedef __attribute__((ext_vector_type(4))) float f32x4;

__device__ __forceinline__ unsigned short f2bf(float f) {
    unsigned int u = __builtin_bit_cast(unsigned int, f);
    unsigned int r = (u + 0x7FFFu + ((u >> 16) & 1u)) >> 16;
    return (unsigned short)r;
}

__device__ __forceinline__ void gld16(const void* g, void* l) {
    __builtin_amdgcn_global_load_lds(
        (const __attribute__((address_space(1))) unsigned int*)g,
        (__attribute__((address_space(3))) unsigned int*)l, 16, 0, 0);
}

// ---------------- prepass: fp32 -> bf16 (8 elems / thread) ----------------
__global__ __launch_bounds__(256) void cvt_bf16_kernel(
    const float* __restrict__ in, uint4* __restrict__ outp, int n8)
{
    int i = blockIdx.x * 256 + threadIdx.x;
    if (i >= n8) return;
    const float4* p = (const float4*)in + 2 * (size_t)i;
    float4 a = p[0];
    float4 b = p[1];
    uint4 w;
    w.x = (unsigned)f2bf(a.x) | ((unsigned)f2bf(a.y) << 16);
    w.y = (unsigned)f2bf(a.z) | ((unsigned)f2bf(a.w) << 16);
    w.z = (unsigned)f2bf(b.x) | ((unsigned)f2bf(b.y) << 16);
    w.w = (unsigned)f2bf(b.z) | ((unsigned)f2bf(b.w) << 16);
    outp[i] = w;
}

// ---------------- main: bf16 MFMA with global_load_lds staging ----------------
__global__ __launch_bounds__(256, 2) void fsl_mfma_bf16_kernel(
    const unsigned short* __restrict__ xb, const unsigned short* __restrict__ vb,
    const float* __restrict__ bias, const int* __restrict__ brows,
    const int* __restrict__ bcols, float* __restrict__ out)
{
    __shared__ __align__(16) unsigned char sA[2][64 * 128];
    __shared__ __align__(16) unsigned char sB[2][64 * 128];
    __shared__ unsigned int s_list[NB];
    __shared__ int s_cnt;

    const int tid  = threadIdx.x;
    const int b    = blockIdx.x;
    // XCD-aware remap: each XCD owns 4 t-tiles x all 64 row-groups.
    // x tiles (4 x 0.5 MB bf16) stay L2-resident; same-r WGs are adjacent.
    const int xcd  = b & 7;
    const int slot = b >> 3;
    const int t0   = (xcd + 8 * (slot & 3)) * 64;
    const int r    = slot >> 2;               // 0..63

    if (tid == 0) s_cnt = 0;
    __syncthreads();
    for (int n = tid; n < NB; n += 256) {
        if (brows[n] == r) {
            int p = atomicAdd(&s_cnt, 1);
            s_list[p] = (unsigned)n | ((unsigned)bcols[n] << 16);
        }
    }
    __syncthreads();
    const int cnt = s_cnt;

    const int wave = tid >> 6;
    const int lane = tid & 63;
    const int wt   = wave >> 1;
    const int wm   = wave & 1;
    const int lrow = lane & 15;
    const int lk8  = (lane >> 4) * 8;

    f32x4 acc[2][2] = {};

    // staging: wave w stages rows [w*16, w*16+16) of both tiles, 2 chunks of
    // 8 rows x 128B each; LDS dest is linear (wave-uniform base + lane*16),
    // swizzle applied by XOR-ing the per-lane GLOBAL source slot (m173).
    const int srr    = lane >> 3;   // row within 8-row chunk
    const int scol16 = lane & 7;    // 16B slot within 128B row

    auto stage = [&](int i, int buf) {
        const unsigned int pc = s_list[i];
        const int n = pc & 0xFFFF;
        const int c = pc >> 16;
#pragma unroll
        for (int ch = 0; ch < 2; ++ch) {
            const int rbase = wave * 16 + ch * 8;
            const int row   = rbase + srr;
            const int sc    = (scol16 ^ (row & 7)) * 8;   // bf16 elem offset
            gld16(xb + (size_t)(t0 + row) * K_DIM + c * 64 + sc,
                  &sA[buf][rbase * 128]);
            gld16(vb + (size_t)n * 4096 + row * 64 + sc,
                  &sB[buf][rbase * 128]);
        }
    };

    auto compute = [&](int buf) {
#pragma unroll
        for (int ks = 0; ks < 2; ++ks) {
            bf16x8 a[2], bfr[2];
#pragma unroll
            for (int f = 0; f < 2; ++f) {
                const int trow = wt * 32 + f * 16 + lrow;
                int abyte = trow * 128 + (ks * 32 + lk8) * 2;
                abyte ^= (trow & 7) << 4;
                a[f] = *(const bf16x8*)(&sA[buf][abyte]);
                const int mrow = wm * 32 + f * 16 + lrow;
                int bbyte = mrow * 128 + (ks * 32 + lk8) * 2;
                bbyte ^= (mrow & 7) << 4;
                bfr[f] = *(const bf16x8*)(&sB[buf][bbyte]);
            }
#pragma unroll
            for (int ft = 0; ft < 2; ++ft)
#pragma unroll
                for (int fm = 0; fm < 2; ++fm)
                    acc[ft][fm] = __builtin_amdgcn_mfma_f32_16x16x32_bf16(
                        a[ft], bfr[fm], acc[ft][fm], 0, 0, 0);
        }
    };

    if (cnt > 0) stage(0, 0);
    __syncthreads();                       // buf0 staged (barrier drains vmcnt)
    for (int i = 0; i < cnt; ++i) {
        if (i + 1 < cnt) stage(i + 1, (i + 1) & 1);  // prefetch in flight...
        compute(i & 1);                              // ...hidden under MFMA
        __syncthreads();                             // drain + guard buf reuse
    }

    // Epilogue: C/D layout col = lane&15 (m index), row = (lane>>4)*4+reg (t)
    const int mcol  = lane & 15;
    const int trow4 = (lane >> 4) * 4;
#pragma unroll
    for (int ft = 0; ft < 2; ++ft) {
#pragma unroll
        for (int fm = 0; fm < 2; ++fm) {
            const int mg = r * 64 + wm * 32 + fm * 16 + mcol;
            const float bv = bias[mg];
#pragma unroll
            for (int reg = 0; reg < 4; ++reg) {
                const int t = t0 + wt * 32 + ft * 16 + trow4 + reg;
                float v = acc[ft][fm][reg] + bv;
                float inner = 0.7978845608f * (v + 0.044715f * v * v * v);
                inner = fminf(fmaxf(inner, -15.0f), 15.0f);
                const float e  = __expf(2.0f * inner);
                const float th = 1.0f - 2.0f / (e + 1.0f);
                out[(size_t)t * M_DIM + mg] = v * 0.5f * (1.0f + th);
            }
        }
    }
}

// ---------------- fallback (round-1 kernel) if ws is too small ----------------
__global__ __launch_bounds__(256, 2) void fsl_mfma_fallback(
    const float* __restrict__ x, const float* __restrict__ values,
    const float* __restrict__ bias, const int* __restrict__ brows,
    const int* __restrict__ bcols, float* __restrict__ out)
{
    __shared__ __align__(16) unsigned char sA[2][64 * 128];
    __shared__ __align__(16) unsigned char sB[2][64 * 128];
    __shared__ int s_list[NB];
    __shared__ int s_cnt;

    const int tid = threadIdx.x;
    const int r   = blockIdx.x >> 5;
    const int t0  = (blockIdx.x & 31) * 64;

    if (tid == 0) s_cnt = 0;
    __syncthreads();
    for (int n = tid; n < NB; n += 256) {
        if (brows[n] == r) {
            int p = atomicAdd(&s_cnt, 1);
            s_list[p] = n;
        }
    }
    __syncthreads();
    const int cnt = s_cnt;

    const int wave = tid >> 6;
    const int lane = tid & 63;
    const int wt   = wave >> 1;
    const int wm   = wave & 1;
    const int lrow = lane & 15;
    const int lk8  = (lane >> 4) * 8;
    const int srow = tid >> 4;
    const int scol = tid & 15;

    f32x4 acc[2][2] = {};
    float4 ra[4], rb[4];

    auto stage_load = [&](int i) {
        const int n = s_list[i];
        const int c = bcols[n];
        const float* xp = x + (size_t)(t0 + srow) * K_DIM + c * 64 + scol * 4;
        const float* vp = values + (size_t)n * 4096 + srow * 64 + scol * 4;
#pragma unroll
        for (int j = 0; j < 4; ++j) {
            ra[j] = *(const float4*)(xp + (size_t)(j * 16) * K_DIM);
            rb[j] = *(const float4*)(vp + j * 16 * 64);
        }
    };
    auto stage_write = [&](int buf) {
#pragma unroll
        for (int j = 0; j < 4; ++j) {
            const int row = srow + j * 16;
            int byte = row * 128 + scol * 8;
            byte ^= (row & 7) << 4;
            uint2 pa, pb;
            pa.x = (unsigned)f2bf(ra[j].x) | ((unsigned)f2bf(ra[j].y) << 16);
            pa.y = (unsigned)f2bf(ra[j].z) | ((unsigned)f2bf(ra[j].w) << 16);
            pb.x = (unsigned)f2bf(rb[j].x) | ((unsigned)f2bf(rb[j].y) << 16);
            pb.y = (unsigned)f2bf(rb[j].z) | ((unsigned)f2bf(rb[j].w) << 16);
            *(uint2*)(&sA[buf][byte]) = pa;
            *(uint2*)(&sB[buf][byte]) = pb;
        }
    };
    auto compute = [&](int buf) {
#pragma unroll
        for (int ks = 0; ks < 2; ++ks) {
            bf16x8 a[2], bb[2];
#pragma unroll
            for (int f = 0; f < 2; ++f) {
                const int trow = wt * 32 + f * 16 + lrow;
                int abyte = trow * 128 + (ks * 32 + lk8) * 2;
                abyte ^= (trow & 7) << 4;
                a[f] = *(const bf16x8*)(&sA[buf][abyte]);
                const int mrow = wm * 32 + f * 16 + lrow;
                int bbyte = mrow * 128 + (ks * 32 + lk8) * 2;
                bbyte ^= (mrow & 7) << 4;
                bb[f] = *(const bf16x8*)(&sB[buf][bbyte]);
            }
#pragma unroll
            for (int ft = 0; ft < 2; ++ft)
#pragma unroll
                for (int fm = 0; fm < 2; ++fm)
                    acc[ft][fm] = __builtin_amdgcn_mfma_f32_16x16x32_bf16(
                        a[ft], bb[fm], acc[ft][fm], 0, 0, 0);
        }
    };

    if (cnt > 0) { stage_load(0); stage_write(0); }
    for (int i = 0; i < cnt; ++i) {
        __syncthreads();
        const bool more = (i + 1 < cnt);
        if (more) stage_load(i + 1);
        compute(i & 1);
        if (more) stage_write((i + 1) & 1);
    }

    const int mcol  = lane & 15;
    const int trow4 = (lane >> 4) * 4;
#pragma unroll
    for (int ft = 0; ft < 2; ++ft) {
#pragma unroll
        for (int fm = 0; fm < 2; ++fm) {
            const int mg = r * 64 + wm * 32 + fm * 16 + mcol;
            const float bv = bias[mg];
#pragma unroll
            for (int reg = 0; reg < 4; ++reg) {
                const int t = t0 + wt * 32 + ft * 16 + trow4 + reg;
                float v = acc[ft][fm][reg] + bv;
                float inner = 0.7978845608f * (v + 0.044715f * v * v * v);
                inner = fminf(fmaxf(inner, -15.0f), 15.0f);
                const float e  = __expf(2.0f * inner);
                const float th = 1.0f - 2.0f / (e + 1.0f);
                out[(size_t)t * M_DIM + mg] = v * 0.5f * (1.0f + th);
            }
        }
    }
}

extern "C" void kernel_launch(void* const* d_in, const int* in_sizes, int n_in,
                              void* d_out, int out_size, void* d_ws, size_t ws_size,
                              hipStream_t stream) {
    const float* x      = (const float*)d_in[0];
    const float* values = (const float*)d_in[1];
    const float* bias   = (const float*)d_in[2];
    const int*   brows  = (const int*)d_in[3];
    const int*   bcols  = (const int*)d_in[4];
    float* out = (float*)d_out;

    const size_t x_elems = (size_t)T_DIM * K_DIM;        // 8,388,608
    const size_t v_elems = (size_t)NB * 64 * 64;         // 4,194,304
    const size_t ws_need = (x_elems + v_elems) * 2;      // 25,165,824 B

    if (ws_size >= ws_need) {
        unsigned short* xb = (unsigned short*)d_ws;
        unsigned short* vb = xb + x_elems;
        const int n8x = (int)(x_elems / 8);
        const int n8v = (int)(v_elems / 8);
        cvt_bf16_kernel<<<(n8x + 255) / 256, 256, 0, stream>>>(x, (uint4*)xb, n8x);
        cvt_bf16_kernel<<<(n8v + 255) / 256, 256, 0, stream>>>(values, (uint4*)vb, n8v);
        fsl_mfma_bf16_kernel<<<dim3(64 * 32), 256, 0, stream>>>(
            xb, vb, bias, brows, bcols, out);
    } else {
        fsl_mfma_fallback<<<dim3(64 * 32), 256, 0, stream>>>(
            x, values, bias, brows, bcols, out);
    }
}

// Round 4
// 140.490 us; speedup vs baseline: 1.2116x; 1.0163x over previous
//
#include <hip/hip_runtime.h>
#include <hip/hip_bf16.h>

#define K_DIM 4096
#define M_DIM 4096
#define T_DIM 2048
#define NB    1024
#define BT    128

typedef __attribute__((ext_vector_type(8))) short bf16x8;
typedef __attribute__((ext_vector_type(4))) float f32x4;

__device__ __forceinline__ unsigned short f2bf(float f) {
    unsigned int u = __builtin_bit_cast(unsigned int, f);
    unsigned int r = (u + 0x7FFFu + ((u >> 16) & 1u)) >> 16;
    return (unsigned short)r;
}

__device__ __forceinline__ void gld16(const void* g, void* l) {
    __builtin_amdgcn_global_load_lds(
        (const __attribute__((address_space(1))) unsigned int*)g,
        (__attribute__((address_space(3))) unsigned int*)l, 16, 0, 0);
}

// ---- fused prepass ----
// part 1: x fp32 [2048][4096] -> xb2 bf16 [64 c][2048 t][64 k]  (transposed)
// part 2: values fp32 -> vb bf16 (linear)
#define XCHUNKS (T_DIM * K_DIM / 8)   // 1,048,576
#define VCHUNKS (NB * 64 * 64 / 8)    //   524,288
__global__ __launch_bounds__(256) void prep_kernel(
    const float* __restrict__ x, const float* __restrict__ values,
    unsigned short* __restrict__ xb2, unsigned short* __restrict__ vb)
{
    const int id = blockIdx.x * 256 + threadIdx.x;
    if (id < XCHUNKS) {
        const int t   = id >> 9;        // 512 8-elem chunks per t-row
        const int rem = id & 511;
        const int c   = rem >> 3;       // col-block 0..63
        const int o   = rem & 7;        // 8-elem offset within 64
        const float4* p = (const float4*)(x + (size_t)t * K_DIM + c * 64 + o * 8);
        const float4 a = p[0], b = p[1];
        uint4 w;
        w.x = (unsigned)f2bf(a.x) | ((unsigned)f2bf(a.y) << 16);
        w.y = (unsigned)f2bf(a.z) | ((unsigned)f2bf(a.w) << 16);
        w.z = (unsigned)f2bf(b.x) | ((unsigned)f2bf(b.y) << 16);
        w.w = (unsigned)f2bf(b.z) | ((unsigned)f2bf(b.w) << 16);
        *(uint4*)(xb2 + ((size_t)c * T_DIM + t) * 64 + o * 8) = w;
    } else if (id < XCHUNKS + VCHUNKS) {
        const int i = id - XCHUNKS;
        const float4* p = (const float4*)(values + (size_t)i * 8);
        const float4 a = p[0], b = p[1];
        uint4 w;
        w.x = (unsigned)f2bf(a.x) | ((unsigned)f2bf(a.y) << 16);
        w.y = (unsigned)f2bf(a.z) | ((unsigned)f2bf(a.w) << 16);
        w.z = (unsigned)f2bf(b.x) | ((unsigned)f2bf(b.y) << 16);
        w.w = (unsigned)f2bf(b.z) | ((unsigned)f2bf(b.w) << 16);
        *(uint4*)(vb + (size_t)i * 8) = w;
    }
}

// ---- main kernel: BT=128 tile, A in swizzled LDS (gld16), B in registers ----
__global__ __launch_bounds__(256, 4) void fsl_main(
    const unsigned short* __restrict__ xb2, const unsigned short* __restrict__ vb,
    const float* __restrict__ bias, const int* __restrict__ brows,
    const int* __restrict__ bcols, float* __restrict__ out)
{
    __shared__ __align__(16) unsigned char sA[2][BT * 128];  // 2 x 16 KB
    __shared__ unsigned int s_list[NB];
    __shared__ int s_cnt;

    const int tid  = threadIdx.x;
    const int b    = blockIdx.x;
    // 1024 WGs: xcd = b&7 owns 2 t-tiles (x slice 2 MB, L2-resident) x 64 r
    const int xcd   = b & 7;
    const int slot  = b >> 3;              // 0..127
    const int ttile = xcd * 2 + (slot & 1);
    const int t0    = ttile * BT;
    const int r     = slot >> 1;           // 0..63

    if (tid == 0) s_cnt = 0;
    __syncthreads();
    for (int n = tid; n < NB; n += 256) {
        if (brows[n] == r) {
            int p = atomicAdd(&s_cnt, 1);
            s_list[p] = (unsigned)n | ((unsigned)bcols[n] << 16);
        }
    }
    __syncthreads();
    const int cnt = s_cnt;

    const int wave = tid >> 6;
    const int lane = tid & 63;
    const int lrow = lane & 15;
    const int lk16 = lane >> 4;            // k-group 0..3 (x8 bf16)

    f32x4 acc[8] = {};                     // 8 t-frags of 16x16

    // staging lanes: per wave 4 chunks of 8 rows x 128B, linear LDS dest,
    // swizzle applied on the GLOBAL source slot (involution with the read XOR)
    const int srr    = lane >> 3;
    const int scol16 = lane & 7;

    auto stageA = [&](int i, int buf) {
        const int c = (int)(s_list[i] >> 16);
        const unsigned short* src = xb2 + ((size_t)c * T_DIM + t0) * 64;
#pragma unroll
        for (int ch = 0; ch < 4; ++ch) {
            const int rbase = wave * 32 + ch * 8;
            const int row   = rbase + srr;
            const int sc    = (scol16 ^ (row & 7)) * 8;
            gld16(src + (size_t)row * 64 + sc, &sA[buf][rbase * 128]);
        }
    };

    auto loadB = [&](int i, bf16x8& b0, bf16x8& b1) {
        const int n = (int)(s_list[i] & 0xFFFF);
        const unsigned short* vp =
            vb + (size_t)n * 4096 + (wave * 16 + lrow) * 64 + lk16 * 8;
        b0 = *(const bf16x8*)(vp);        // ks=0 fragment
        b1 = *(const bf16x8*)(vp + 32);   // ks=1 fragment
    };

    auto compute = [&](int buf, bf16x8 b0, bf16x8 b1) {
#pragma unroll
        for (int ks = 0; ks < 2; ++ks) {
            bf16x8 afr[8];
#pragma unroll
            for (int tf = 0; tf < 8; ++tf) {
                const int trow = tf * 16 + lrow;
                int abyte = trow * 128 + (ks * 32 + lk16 * 8) * 2;
                abyte ^= (trow & 7) << 4;
                afr[tf] = *(const bf16x8*)(&sA[buf][abyte]);
            }
            const bf16x8 bb = ks ? b1 : b0;
#pragma unroll
            for (int tf = 0; tf < 8; ++tf)
                acc[tf] = __builtin_amdgcn_mfma_f32_16x16x32_bf16(
                    afr[tf], bb, acc[tf], 0, 0, 0);
        }
    };

    bf16x8 b0e, b1e, b0o, b1o;
    if (cnt > 0) { stageA(0, 0); loadB(0, b0e, b1e); }
    // unroll-2 pipeline: counted vmcnt (6 = this iter's 4 gld16 + 2 B-loads);
    // barriers are raw (no drain); cross-wave gld16->ds_read is what they guard.
    for (int i = 0; i < cnt; i += 2) {
        {   // even sub-iter: buf 0, consumes (b0e,b1e), prefetches odd
            if (i + 1 < cnt) {
                stageA(i + 1, 1);
                loadB(i + 1, b0o, b1o);
                asm volatile("s_waitcnt vmcnt(6)" ::: "memory");
            } else {
                asm volatile("s_waitcnt vmcnt(0)" ::: "memory");
            }
            __builtin_amdgcn_s_barrier();
            compute(0, b0e, b1e);
            __builtin_amdgcn_s_barrier();
        }
        if (i + 1 < cnt) {  // odd sub-iter: buf 1
            if (i + 2 < cnt) {
                stageA(i + 2, 0);
                loadB(i + 2, b0e, b1e);
                asm volatile("s_waitcnt vmcnt(6)" ::: "memory");
            } else {
                asm volatile("s_waitcnt vmcnt(0)" ::: "memory");
            }
            __builtin_amdgcn_s_barrier();
            compute(1, b0o, b1o);
            __builtin_amdgcn_s_barrier();
        }
    }

    // Epilogue: C/D layout col(lane&15)=m, row((lane>>4)*4+reg)=t
    const int mg = r * 64 + wave * 16 + (lane & 15);
    const float bv = bias[mg];
    const int tbase = t0 + (lane >> 4) * 4;
#pragma unroll
    for (int tf = 0; tf < 8; ++tf) {
#pragma unroll
        for (int reg = 0; reg < 4; ++reg) {
            const int t = tbase + tf * 16 + reg;
            float v = acc[tf][reg] + bv;
            float inner = 0.7978845608f * (v + 0.044715f * v * v * v);
            inner = fminf(fmaxf(inner, -15.0f), 15.0f);
            const float e  = __expf(2.0f * inner);
            const float th = 1.0f - 2.0f / (e + 1.0f);
            out[(size_t)t * M_DIM + mg] = v * 0.5f * (1.0f + th);
        }
    }
}

// ---- fallback (round-1 fp32 kernel) if ws is too small ----
__global__ __launch_bounds__(256, 2) void fsl_mfma_fallback(
    const float* __restrict__ x, const float* __restrict__ values,
    const float* __restrict__ bias, const int* __restrict__ brows,
    const int* __restrict__ bcols, float* __restrict__ out)
{
    __shared__ __align__(16) unsigned char sA[2][64 * 128];
    __shared__ __align__(16) unsigned char sB[2][64 * 128];
    __shared__ int s_list[NB];
    __shared__ int s_cnt;

    const int tid = threadIdx.x;
    const int r   = blockIdx.x >> 5;
    const int t0  = (blockIdx.x & 31) * 64;

    if (tid == 0) s_cnt = 0;
    __syncthreads();
    for (int n = tid; n < NB; n += 256) {
        if (brows[n] == r) {
            int p = atomicAdd(&s_cnt, 1);
            s_list[p] = n;
        }
    }
    __syncthreads();
    const int cnt = s_cnt;

    const int wave = tid >> 6;
    const int lane = tid & 63;
    const int wt   = wave >> 1;
    const int wm   = wave & 1;
    const int lrow = lane & 15;
    const int lk8  = (lane >> 4) * 8;
    const int srow = tid >> 4;
    const int scol = tid & 15;

    f32x4 acc[2][2] = {};
    float4 ra[4], rb[4];

    auto stage_load = [&](int i) {
        const int n = s_list[i];
        const int c = bcols[n];
        const float* xp = x + (size_t)(t0 + srow) * K_DIM + c * 64 + scol * 4;
        const float* vp = values + (size_t)n * 4096 + srow * 64 + scol * 4;
#pragma unroll
        for (int j = 0; j < 4; ++j) {
            ra[j] = *(const float4*)(xp + (size_t)(j * 16) * K_DIM);
            rb[j] = *(const float4*)(vp + j * 16 * 64);
        }
    };
    auto stage_write = [&](int buf) {
#pragma unroll
        for (int j = 0; j < 4; ++j) {
            const int row = srow + j * 16;
            int byte = row * 128 + scol * 8;
            byte ^= (row & 7) << 4;
            uint2 pa, pb;
            pa.x = (unsigned)f2bf(ra[j].x) | ((unsigned)f2bf(ra[j].y) << 16);
            pa.y = (unsigned)f2bf(ra[j].z) | ((unsigned)f2bf(ra[j].w) << 16);
            pb.x = (unsigned)f2bf(rb[j].x) | ((unsigned)f2bf(rb[j].y) << 16);
            pb.y = (unsigned)f2bf(rb[j].z) | ((unsigned)f2bf(rb[j].w) << 16);
            *(uint2*)(&sA[buf][byte]) = pa;
            *(uint2*)(&sB[buf][byte]) = pb;
        }
    };
    auto compute = [&](int buf) {
#pragma unroll
        for (int ks = 0; ks < 2; ++ks) {
            bf16x8 a[2], bb[2];
#pragma unroll
            for (int f = 0; f < 2; ++f) {
                const int trow = wt * 32 + f * 16 + lrow;
                int abyte = trow * 128 + (ks * 32 + lk8) * 2;
                abyte ^= (trow & 7) << 4;
                a[f] = *(const bf16x8*)(&sA[buf][abyte]);
                const int mrow = wm * 32 + f * 16 + lrow;
                int bbyte = mrow * 128 + (ks * 32 + lk8) * 2;
                bbyte ^= (mrow & 7) << 4;
                bb[f] = *(const bf16x8*)(&sB[buf][bbyte]);
            }
#pragma unroll
            for (int ft = 0; ft < 2; ++ft)
#pragma unroll
                for (int fm = 0; fm < 2; ++fm)
                    acc[ft][fm] = __builtin_amdgcn_mfma_f32_16x16x32_bf16(
                        a[ft], bb[fm], acc[ft][fm], 0, 0, 0);
        }
    };

    if (cnt > 0) { stage_load(0); stage_write(0); }
    for (int i = 0; i < cnt; ++i) {
        __syncthreads();
        const bool more = (i + 1 < cnt);
        if (more) stage_load(i + 1);
        compute(i & 1);
        if (more) stage_write((i + 1) & 1);
    }

    const int mcol  = lane & 15;
    const int trow4 = (lane >> 4) * 4;
#pragma unroll
    for (int ft = 0; ft < 2; ++ft) {
#pragma unroll
        for (int fm = 0; fm < 2; ++fm) {
            const int mg = r * 64 + wm * 32 + fm * 16 + mcol;
            const float bv = bias[mg];
#pragma unroll
            for (int reg = 0; reg < 4; ++reg) {
                const int t = t0 + wt * 32 + ft * 16 + trow4 + reg;
                float v = acc[ft][fm][reg] + bv;
                float inner = 0.7978845608f * (v + 0.044715f * v * v * v);
                inner = fminf(fmaxf(inner, -15.0f), 15.0f);
                const float e  = __expf(2.0f * inner);
                const float th = 1.0f - 2.0f / (e + 1.0f);
                out[(size_t)t * M_DIM + mg] = v * 0.5f * (1.0f + th);
            }
        }
    }
}

extern "C" void kernel_launch(void* const* d_in, const int* in_sizes, int n_in,
                              void* d_out, int out_size, void* d_ws, size_t ws_size,
                              hipStream_t stream) {
    const float* x      = (const float*)d_in[0];
    const float* values = (const float*)d_in[1];
    const float* bias   = (const float*)d_in[2];
    const int*   brows  = (const int*)d_in[3];
    const int*   bcols  = (const int*)d_in[4];
    float* out = (float*)d_out;

    const size_t x_elems = (size_t)T_DIM * K_DIM;
    const size_t v_elems = (size_t)NB * 64 * 64;
    const size_t ws_need = (x_elems + v_elems) * 2;

    if (ws_size >= ws_need) {
        unsigned short* xb2 = (unsigned short*)d_ws;
        unsigned short* vb  = xb2 + x_elems;
        prep_kernel<<<(XCHUNKS + VCHUNKS) / 256, 256, 0, stream>>>(x, values, xb2, vb);
        fsl_main<<<dim3(1024), 256, 0, stream>>>(xb2, vb, bias, brows, bcols, out);
    } else {
        fsl_mfma_fallback<<<dim3(64 * 32), 256, 0, stream>>>(
            x, values, bias, brows, bcols, out);
    }
}